// Round 1
// baseline (68.127 us; speedup 1.0000x reference)
//
#include <hip/hip_runtime.h>
#include <hip/hip_bf16.h>

typedef __attribute__((ext_vector_type(4))) float  f4;
typedef __attribute__((ext_vector_type(8))) short  short8;
typedef __attribute__((ext_vector_type(4))) float  f32x4;

static constexpr int NHEAD = 16;
static constexpr int NIN   = 128;
static constexpr int NOUT  = 128;
static constexpr int NROWS = 8 * 2048;          // B*S = 16384
static constexpr int RSTR  = NHEAD * NIN;       // 2048 floats per (b,s) row
static constexpr int BLOCKS_PER_HEAD = 64;
static constexpr int ROWS_PER_BLOCK  = NROWS / BLOCKS_PER_HEAD;  // 256
static constexpr int ITERS = ROWS_PER_BLOCK / 64;                // 4 (64 rows per WG iter)

static __device__ inline unsigned short f2bfu(float f) {
  union { __hip_bfloat16 h; unsigned short u; } v;
  v.h = __float2bfloat16(f);
  return v.u;
}

static __device__ inline short8 cvt8(f4 a, f4 b) {
  short8 r;
  r[0] = (short)f2bfu(a[0]); r[1] = (short)f2bfu(a[1]);
  r[2] = (short)f2bfu(a[2]); r[3] = (short)f2bfu(a[3]);
  r[4] = (short)f2bfu(b[0]); r[5] = (short)f2bfu(b[1]);
  r[6] = (short)f2bfu(b[2]); r[7] = (short)f2bfu(b[3]);
  return r;
}

__global__ __launch_bounds__(256)
void bdp_kernel(const float* __restrict__ X, const float* __restrict__ W,
                float* __restrict__ O) {
  // B-fragments of W^T for head `blockIdx.y`, fragment-contiguous:
  // frag id = n*4 + kk (n = 16-col tile 0..7, kk = 32-wide k-step 0..3),
  // lane-major inside a fragment -> ds_read_b128 is 64x consecutive 16B.
  __shared__ short8 wtile[32][64];

  const int head = blockIdx.y;
  const int tid  = (int)threadIdx.x;
  const int lane = tid & 63;
  const int wid  = tid >> 6;      // 4 waves
  const int lr   = lane & 15;     // row (A) / col (B,C) within 16
  const int lq   = lane >> 4;     // 0..3 quarter-wave

  // ---- stage W(head) -> LDS as bf16 MFMA B-fragments ----
  // B[k][col] = W[col][k]; frag(n,kk): lane holds col = n*16 + (lane&15),
  // k = kk*32 + (lane>>4)*8 + j, j=0..7 contiguous in i.
  const float* Wh = W + (size_t)head * NOUT * NIN;
  #pragma unroll
  for (int it = 0; it < 8; ++it) {
    const int o = it * 16 + lr;            // W row (= output col)
    const int i = wid * 32 + lq * 8;       // W col (= k), wid -> kk
    const float* src = Wh + o * NIN + i;
    f4 a = *reinterpret_cast<const f4*>(src);
    f4 b = *reinterpret_cast<const f4*>(src + 4);
    wtile[it * 4 + wid][lane] = cvt8(a, b);  // frag = n*4 + kk, n = it
  }
  __syncthreads();

  const int rowbase = (int)blockIdx.x * ROWS_PER_BLOCK;

  for (int itr = 0; itr < ITERS; ++itr) {
    const int row0 = rowbase + itr * 64 + wid * 16;   // this wave's 16 rows
    const float* xr = X + (size_t)(row0 + lr) * RSTR + head * NIN;

    f32x4 acc[8];
    #pragma unroll
    for (int n = 0; n < 8; ++n) acc[n] = (f32x4){0.f, 0.f, 0.f, 0.f};

    #pragma unroll
    for (int kk = 0; kk < 4; ++kk) {
      const int koff = kk * 32 + lq * 8;
      f4 a = *reinterpret_cast<const f4*>(xr + koff);
      f4 b = *reinterpret_cast<const f4*>(xr + koff + 4);
      short8 av = cvt8(a, b);               // A frag: row = lane&15, k = koff..koff+7
      #pragma unroll
      for (int n = 0; n < 8; ++n) {
        acc[n] = __builtin_amdgcn_mfma_f32_16x16x32_bf16(
            av, wtile[n * 4 + kk][lane], acc[n], 0, 0, 0);
      }
    }

    // C/D layout: col = lane&15, row = (lane>>4)*4 + reg  [m89-verified]
    float* orow = O + (size_t)row0 * RSTR + head * NOUT;
    #pragma unroll
    for (int n = 0; n < 8; ++n) {
      #pragma unroll
      for (int j = 0; j < 4; ++j) {
        orow[(size_t)(lq * 4 + j) * RSTR + n * 16 + lr] = acc[n][j];
      }
    }
  }
}

extern "C" void kernel_launch(void* const* d_in, const int* in_sizes, int n_in,
                              void* d_out, int out_size, void* d_ws, size_t ws_size,
                              hipStream_t stream) {
  const float* X = (const float*)d_in[0];   // [8,2048,16,128] f32
  const float* W = (const float*)d_in[1];   // [16,128,128] f32
  float* O = (float*)d_out;                 // [8,2048,16,128] f32
  dim3 grid(BLOCKS_PER_HEAD, NHEAD);
  bdp_kernel<<<grid, dim3(256), 0, stream>>>(X, W, O);
}

// Round 3
// 61.003 us; speedup vs baseline: 1.1168x; 1.1168x over previous
//
#include <hip/hip_runtime.h>
#include <hip/hip_bf16.h>

typedef __attribute__((ext_vector_type(4))) float  f4;
typedef __attribute__((ext_vector_type(8))) short  short8;
typedef __attribute__((ext_vector_type(4))) float  f32x4;

static constexpr int NHEAD = 16;
static constexpr int NIN   = 128;
static constexpr int NOUT  = 128;
static constexpr int NROWS = 8 * 2048;          // B*S = 16384
static constexpr int RSTR  = NHEAD * NIN;       // 2048 floats per (b,s) row
static constexpr int ROWS_PER_BLOCK = 128;      // 8 waves x 16 rows, single shot
static constexpr int BLOCKS_X = NROWS / ROWS_PER_BLOCK;  // 128

static __device__ inline unsigned short f2bfu(float f) {
  union { __hip_bfloat16 h; unsigned short u; } v;
  v.h = __float2bfloat16(f);
  return v.u;
}

static __device__ inline short8 cvt8(f4 a, f4 b) {
  short8 r;
  r[0] = (short)f2bfu(a[0]); r[1] = (short)f2bfu(a[1]);
  r[2] = (short)f2bfu(a[2]); r[3] = (short)f2bfu(a[3]);
  r[4] = (short)f2bfu(b[0]); r[5] = (short)f2bfu(b[1]);
  r[6] = (short)f2bfu(b[2]); r[7] = (short)f2bfu(b[3]);
  return r;
}

__global__ __launch_bounds__(512)
void bdp_kernel(const float* __restrict__ X, const float* __restrict__ W,
                float* __restrict__ O) {
  // W(head) as bf16 MFMA fragments, fragment-contiguous (zero bank conflict):
  // frag = n*4 + kk; lane holds index o = n*16 + (lane&15), k = kk*32 + (lane>>4)*8 + j.
  // Used as the A operand (A/B per-lane layouts are symmetric for 16x16x32).
  __shared__ short8 wtile[32][64];

  const int head = blockIdx.y;
  const int tid  = (int)threadIdx.x;
  const int lane = tid & 63;
  const int wid  = tid >> 6;      // 8 waves
  const int lr   = lane & 15;
  const int lq   = lane >> 4;

  const int row0 = (int)blockIdx.x * ROWS_PER_BLOCK + wid * 16;  // wave's 16 rows
  const float* xr = X + (size_t)(row0 + lr) * RSTR + head * NIN;

  // ---- issue all X loads first: they drain under W-staging + barrier ----
  f4 xa[4], xb[4];
  #pragma unroll
  for (int kk = 0; kk < 4; ++kk) {
    const int koff = kk * 32 + lq * 8;
    xa[kk] = *reinterpret_cast<const f4*>(xr + koff);
    xb[kk] = *reinterpret_cast<const f4*>(xr + koff + 4);
  }

  // ---- stage W(head): each wave writes 4 of the 32 fragments ----
  const float* Wh = W + (size_t)head * NOUT * NIN;
  #pragma unroll
  for (int it = 0; it < 4; ++it) {
    const int frag = wid * 4 + it;
    const int n  = frag >> 2;
    const int kk = frag & 3;
    const float* src = Wh + (n * 16 + lr) * NIN + kk * 32 + lq * 8;
    f4 a = *reinterpret_cast<const f4*>(src);
    f4 b = *reinterpret_cast<const f4*>(src + 4);
    wtile[frag][lane] = cvt8(a, b);
  }
  __syncthreads();

  // ---- convert X (loads complete by now), then MFMA ----
  short8 xv[4];
  #pragma unroll
  for (int kk = 0; kk < 4; ++kk) xv[kk] = cvt8(xa[kk], xb[kk]);

  f32x4 acc[8];
  #pragma unroll
  for (int n = 0; n < 8; ++n) acc[n] = (f32x4){0.f, 0.f, 0.f, 0.f};

  #pragma unroll
  for (int kk = 0; kk < 4; ++kk) {
    #pragma unroll
    for (int n = 0; n < 8; ++n) {
      // A = W frag (rows = o), B = X frag (cols = x-row)
      acc[n] = __builtin_amdgcn_mfma_f32_16x16x32_bf16(
          wtile[n * 4 + kk][lane], xv[kk], acc[n], 0, 0, 0);
    }
  }

  // D[o][xrow]: lane holds xrow = lane&15 (col), o = n*16 + (lane>>4)*4 + reg.
  // The 4 regs are CONSECUTIVE o -> one dwordx4 (nontemporal, write-once) each.
  float* dst = O + (size_t)(row0 + lr) * RSTR + head * NOUT;
  #pragma unroll
  for (int n = 0; n < 8; ++n) {
    __builtin_nontemporal_store(acc[n], reinterpret_cast<f4*>(dst + n * 16 + lq * 4));
  }
}

extern "C" void kernel_launch(void* const* d_in, const int* in_sizes, int n_in,
                              void* d_out, int out_size, void* d_ws, size_t ws_size,
                              hipStream_t stream) {
  const float* X = (const float*)d_in[0];   // [8,2048,16,128] f32
  const float* W = (const float*)d_in[1];   // [16,128,128] f32
  float* O = (float*)d_out;                 // [8,2048,16,128] f32
  dim3 grid(BLOCKS_X, NHEAD);
  bdp_kernel<<<grid, dim3(512), 0, stream>>>(X, W, O);
}